// Round 1
// baseline (940.421 us; speedup 1.0000x reference)
//
#include <hip/hip_runtime.h>
#include <math.h>

#define N_NODES 100000
#define N_EDGES 1600000
#define D_IN 256
#define D_OUT 128

#define BN 64
#define BK 32

// ---------------------------------------------------------------------------
// GEMM: support[n][f] = sum_k input[n][k] * W[k][f] + b[f]
// 256 threads/block, block tile = 64 nodes x 128 feats, k-chunk 32.
// Micro-tile per thread: 8 nodes x 4 feats (fg = t&31 -> feats, ng = t>>5 -> nodes).
// Per k-step: 3x ds_read_b128 + 32x v_fma_f32 -> VALU-bound.
// ---------------------------------------------------------------------------
__global__ __launch_bounds__(256) void gemm_kernel(
    const float* __restrict__ input, const float* __restrict__ W,
    const float* __restrict__ b, float* __restrict__ support) {
  __shared__ float As[BK][BN + 4];   // +4 pad keeps 16B alignment, shifts banks
  __shared__ float Ws[BK][D_OUT];

  const int t = threadIdx.x;
  const int node0 = blockIdx.x * BN;
  const int fg = t & 31;   // feature group: feats fg*4 .. fg*4+3
  const int ng = t >> 5;   // node group:    nodes ng*8 .. ng*8+7

  float acc[8][4];
#pragma unroll
  for (int i = 0; i < 8; i++)
#pragma unroll
    for (int j = 0; j < 4; j++) acc[i][j] = 0.f;

  for (int k0 = 0; k0 < D_IN; k0 += BK) {
    // Stage A tile transposed: As[k][n]; 64 nodes x 32 k = 512 float4 loads.
#pragma unroll
    for (int j = 0; j < 2; j++) {
      int i = t + j * 256;
      int an = i >> 3;            // 0..63
      int ak = (i & 7) << 2;      // 0,4,...,28
      float4 v = make_float4(0.f, 0.f, 0.f, 0.f);
      if (node0 + an < N_NODES)
        v = *(const float4*)(input + (size_t)(node0 + an) * D_IN + k0 + ak);
      As[ak + 0][an] = v.x;
      As[ak + 1][an] = v.y;
      As[ak + 2][an] = v.z;
      As[ak + 3][an] = v.w;
    }
    // Stage W tile: 32 k x 128 f = 1024 float4 loads.
#pragma unroll
    for (int j = 0; j < 4; j++) {
      int i = t + j * 256;
      int wk = i >> 5;            // 0..31
      int wf = (i & 31) << 2;     // 0,4,...,124
      *(float4*)&Ws[wk][wf] = *(const float4*)(W + (size_t)(k0 + wk) * D_OUT + wf);
    }
    __syncthreads();

#pragma unroll 8
    for (int k = 0; k < BK; k++) {
      float4 w4 = *(const float4*)&Ws[k][fg << 2];
      float4 a0 = *(const float4*)&As[k][ng << 3];
      float4 a1 = *(const float4*)&As[k][(ng << 3) + 4];
      float a[8] = {a0.x, a0.y, a0.z, a0.w, a1.x, a1.y, a1.z, a1.w};
      float w[4] = {w4.x, w4.y, w4.z, w4.w};
#pragma unroll
      for (int i = 0; i < 8; i++)
#pragma unroll
        for (int j = 0; j < 4; j++)
          acc[i][j] = fmaf(a[i], w[j], acc[i][j]);
    }
    __syncthreads();
  }

  const float4 bv = *(const float4*)(b + (fg << 2));
#pragma unroll
  for (int i = 0; i < 8; i++) {
    int n = node0 + (ng << 3) + i;
    if (n < N_NODES) {
      float4 o;
      o.x = acc[i][0] + bv.x;
      o.y = acc[i][1] + bv.y;
      o.z = acc[i][2] + bv.z;
      o.w = acc[i][3] + bv.w;
      *(float4*)(support + (size_t)n * D_OUT + (fg << 2)) = o;
    }
  }
}

// ---------------------------------------------------------------------------
// Edge scatter: out[row[e]][f] += val[e] * support[col[e]][f]
// 2 edges per 256-thread block; one wave-pair (128 threads) per edge so
// row/col/val are wave-uniform and the 128-wide feature access is coalesced.
// ---------------------------------------------------------------------------
__global__ __launch_bounds__(256) void scatter_kernel(
    const int* __restrict__ erow, const int* __restrict__ ecol,
    const float* __restrict__ eval, const float* __restrict__ support,
    float* __restrict__ out) {
  int e = blockIdx.x * 2 + (threadIdx.x >> 7);
  int f = threadIdx.x & 127;
  if (e >= N_EDGES) return;
  int r = erow[e];
  int c = ecol[e];
  float v = eval[e];
  float s = support[(size_t)c * D_OUT + f];
  atomicAdd(out + (size_t)r * D_OUT + f, v * s);
}

// ---------------------------------------------------------------------------
// In-place tanh over 12.8M floats, float4-vectorized (3.2M lanes).
// ---------------------------------------------------------------------------
__global__ __launch_bounds__(256) void tanh_kernel(float* __restrict__ out) {
  size_t i = ((size_t)blockIdx.x * 256 + threadIdx.x) * 4;
  float4 v = *(float4*)(out + i);
  v.x = tanhf(v.x);
  v.y = tanhf(v.y);
  v.z = tanhf(v.z);
  v.w = tanhf(v.w);
  *(float4*)(out + i) = v;
}

extern "C" void kernel_launch(void* const* d_in, const int* in_sizes, int n_in,
                              void* d_out, int out_size, void* d_ws, size_t ws_size,
                              hipStream_t stream) {
  const float* input = (const float*)d_in[0];
  const int* erow = (const int*)d_in[1];
  const int* ecol = (const int*)d_in[2];
  const float* eval = (const float*)d_in[3];
  const float* W = (const float*)d_in[4];
  const float* b = (const float*)d_in[5];
  float* out = (float*)d_out;
  float* support = (float*)d_ws;  // 100000*128*4 = 51.2 MB scratch

  // support = X*W + b
  hipLaunchKernelGGL(gemm_kernel, dim3((N_NODES + BN - 1) / BN), dim3(256), 0,
                     stream, input, W, b, support);
  // zero accumulator (d_out is poisoned 0xAA before every timed launch)
  hipMemsetAsync(d_out, 0, (size_t)out_size * sizeof(float), stream);
  // out += scatter(edges)
  hipLaunchKernelGGL(scatter_kernel, dim3(N_EDGES / 2), dim3(256), 0, stream,
                     erow, ecol, eval, support, out);
  // out = tanh(out)
  hipLaunchKernelGGL(tanh_kernel, dim3((out_size / 4 + 255) / 256), dim3(256),
                     0, stream, out);
}

// Round 2
// 588.987 us; speedup vs baseline: 1.5967x; 1.5967x over previous
//
#include <hip/hip_runtime.h>
#include <math.h>

#define N_NODES 100000
#define N_EDGES 1600000
#define D_IN 256
#define D_OUT 128

#define BN 64
#define BK 32

// ---- workspace layout (bytes) ------------------------------------------
// support : float[N_NODES*D_OUT]                @ 0          (51,200,000)
// counts  : int[N_NODES+1] (becomes offsets)    @ 51,200,000 (   400,004)
// cursor  : int[N_NODES]                        @ 51,600,128 (   400,000)
// csr_col : int[N_EDGES]                        @ 52,000,128 ( 6,400,000)
// csr_val : float[N_EDGES]                      @ 58,400,128 ( 6,400,000)
// bsums   : int[SCAN_BLOCKS]                    @ 64,800,128 (       392)
// total ~64.8 MB
#define OFF_SUPPORT 0
#define OFF_COUNTS  51200000
#define OFF_CURSOR  51600128
#define OFF_CSRCOL  52000128
#define OFF_CSRVAL  58400128
#define OFF_BSUMS   64800128

#define SCAN_CHUNK  1024
#define SCAN_BLOCKS ((N_NODES + SCAN_CHUNK - 1) / SCAN_CHUNK)  // 98

// ---------------------------------------------------------------------------
// GEMM: support[n][f] = sum_k input[n][k] * W[k][f] + b[f]   (unchanged)
// ---------------------------------------------------------------------------
__global__ __launch_bounds__(256) void gemm_kernel(
    const float* __restrict__ input, const float* __restrict__ W,
    const float* __restrict__ b, float* __restrict__ support) {
  __shared__ float As[BK][BN + 4];
  __shared__ float Ws[BK][D_OUT];

  const int t = threadIdx.x;
  const int node0 = blockIdx.x * BN;
  const int fg = t & 31;
  const int ng = t >> 5;

  float acc[8][4];
#pragma unroll
  for (int i = 0; i < 8; i++)
#pragma unroll
    for (int j = 0; j < 4; j++) acc[i][j] = 0.f;

  for (int k0 = 0; k0 < D_IN; k0 += BK) {
#pragma unroll
    for (int j = 0; j < 2; j++) {
      int i = t + j * 256;
      int an = i >> 3;
      int ak = (i & 7) << 2;
      float4 v = make_float4(0.f, 0.f, 0.f, 0.f);
      if (node0 + an < N_NODES)
        v = *(const float4*)(input + (size_t)(node0 + an) * D_IN + k0 + ak);
      As[ak + 0][an] = v.x;
      As[ak + 1][an] = v.y;
      As[ak + 2][an] = v.z;
      As[ak + 3][an] = v.w;
    }
#pragma unroll
    for (int j = 0; j < 4; j++) {
      int i = t + j * 256;
      int wk = i >> 5;
      int wf = (i & 31) << 2;
      *(float4*)&Ws[wk][wf] = *(const float4*)(W + (size_t)(k0 + wk) * D_OUT + wf);
    }
    __syncthreads();

#pragma unroll 8
    for (int k = 0; k < BK; k++) {
      float4 w4 = *(const float4*)&Ws[k][fg << 2];
      float4 a0 = *(const float4*)&As[k][ng << 3];
      float4 a1 = *(const float4*)&As[k][(ng << 3) + 4];
      float a[8] = {a0.x, a0.y, a0.z, a0.w, a1.x, a1.y, a1.z, a1.w};
      float w[4] = {w4.x, w4.y, w4.z, w4.w};
#pragma unroll
      for (int i = 0; i < 8; i++)
#pragma unroll
        for (int j = 0; j < 4; j++)
          acc[i][j] = fmaf(a[i], w[j], acc[i][j]);
    }
    __syncthreads();
  }

  const float4 bv = *(const float4*)(b + (fg << 2));
#pragma unroll
  for (int i = 0; i < 8; i++) {
    int n = node0 + (ng << 3) + i;
    if (n < N_NODES) {
      float4 o;
      o.x = acc[i][0] + bv.x;
      o.y = acc[i][1] + bv.y;
      o.z = acc[i][2] + bv.z;
      o.w = acc[i][3] + bv.w;
      *(float4*)(support + (size_t)n * D_OUT + (fg << 2)) = o;
    }
  }
}

// ---------------------------------------------------------------------------
// CSR build: histogram -> 3-phase exclusive scan -> bucket scatter
// ---------------------------------------------------------------------------
__global__ __launch_bounds__(256) void hist_kernel(const int* __restrict__ erow,
                                                   int* __restrict__ counts) {
  int e = blockIdx.x * 256 + threadIdx.x;
  if (e < N_EDGES) atomicAdd(&counts[erow[e]], 1);
}

__global__ __launch_bounds__(256) void scan_phase1(const int* __restrict__ counts,
                                                   int* __restrict__ bsums) {
  __shared__ int ts[256];
  int t = threadIdx.x;
  int idx0 = blockIdx.x * SCAN_CHUNK + t * 4;
  int s = 0;
#pragma unroll
  for (int i = 0; i < 4; i++)
    if (idx0 + i < N_NODES) s += counts[idx0 + i];
  ts[t] = s;
  __syncthreads();
#pragma unroll
  for (int off = 128; off > 0; off >>= 1) {
    if (t < off) ts[t] += ts[t + off];
    __syncthreads();
  }
  if (t == 0) bsums[blockIdx.x] = ts[0];
}

__global__ __launch_bounds__(128) void scan_phase2(int* __restrict__ bsums) {
  __shared__ int s[128];
  int t = threadIdx.x;
  int v = (t < SCAN_BLOCKS) ? bsums[t] : 0;
  s[t] = v;
  __syncthreads();
#pragma unroll
  for (int off = 1; off < 128; off <<= 1) {
    int x = (t >= off) ? s[t - off] : 0;
    __syncthreads();
    s[t] += x;
    __syncthreads();
  }
  if (t < SCAN_BLOCKS) bsums[t] = s[t] - v;  // exclusive
}

__global__ __launch_bounds__(256) void scan_phase3(int* __restrict__ counts,
                                                   const int* __restrict__ bsums) {
  __shared__ int ts[256];
  int t = threadIdx.x;
  int b = blockIdx.x;
  int idx0 = b * SCAN_CHUNK + t * 4;
  int v[4];
  int s = 0;
#pragma unroll
  for (int i = 0; i < 4; i++) {
    v[i] = (idx0 + i < N_NODES) ? counts[idx0 + i] : 0;
    s += v[i];
  }
  ts[t] = s;
  __syncthreads();
#pragma unroll
  for (int off = 1; off < 256; off <<= 1) {
    int x = (t >= off) ? ts[t - off] : 0;
    __syncthreads();
    ts[t] += x;
    __syncthreads();
  }
  int run = bsums[b] + ts[t] - s;  // exclusive prefix for this thread's 4
#pragma unroll
  for (int i = 0; i < 4; i++) {
    int idx = idx0 + i;
    if (idx < N_NODES) counts[idx] = run;
    run += v[i];
  }
  if (b == 0 && t == 0) counts[N_NODES] = N_EDGES;
}

__global__ __launch_bounds__(256) void build_kernel(
    const int* __restrict__ erow, const int* __restrict__ ecol,
    const float* __restrict__ eval, const int* __restrict__ offsets,
    int* __restrict__ cursor, int* __restrict__ csr_col,
    float* __restrict__ csr_val) {
  int e = blockIdx.x * 256 + threadIdx.x;
  if (e >= N_EDGES) return;
  int r = erow[e];
  int pos = atomicAdd(&cursor[r], 1);
  int idx = offsets[r] + pos;
  csr_col[idx] = ecol[e];
  csr_val[idx] = eval[e];
}

// ---------------------------------------------------------------------------
// Gather-aggregate + fused tanh: one 128-thread block per node.
// Edge metadata loads are wave-uniform (scalar-load eligible); support row
// gathers are 512B coalesced. acc in registers; out written exactly once.
// ---------------------------------------------------------------------------
__global__ __launch_bounds__(128) void agg_kernel(
    const int* __restrict__ offsets, const int* __restrict__ csr_col,
    const float* __restrict__ csr_val, const float* __restrict__ support,
    float* __restrict__ out) {
  int r = blockIdx.x;
  int f = threadIdx.x;
  int beg = offsets[r];
  int end = offsets[r + 1];
  float acc = 0.f;
  for (int j = beg; j < end; j++) {
    int c = csr_col[j];     // uniform per block -> scalar load
    float v = csr_val[j];
    acc = fmaf(v, support[(size_t)c * D_OUT + f], acc);
  }
  out[(size_t)r * D_OUT + f] = tanhf(acc);
}

extern "C" void kernel_launch(void* const* d_in, const int* in_sizes, int n_in,
                              void* d_out, int out_size, void* d_ws, size_t ws_size,
                              hipStream_t stream) {
  const float* input = (const float*)d_in[0];
  const int* erow = (const int*)d_in[1];
  const int* ecol = (const int*)d_in[2];
  const float* eval = (const float*)d_in[3];
  const float* W = (const float*)d_in[4];
  const float* b = (const float*)d_in[5];
  float* out = (float*)d_out;

  char* ws = (char*)d_ws;
  float* support = (float*)(ws + OFF_SUPPORT);
  int* counts = (int*)(ws + OFF_COUNTS);   // becomes offsets after scan
  int* cursor = (int*)(ws + OFF_CURSOR);
  int* csr_col = (int*)(ws + OFF_CSRCOL);
  float* csr_val = (float*)(ws + OFF_CSRVAL);
  int* bsums = (int*)(ws + OFF_BSUMS);

  // support = X*W + b
  hipLaunchKernelGGL(gemm_kernel, dim3((N_NODES + BN - 1) / BN), dim3(256), 0,
                     stream, input, W, b, support);

  // zero counts + cursor in one memset (covers both regions incl. padding)
  hipMemsetAsync(ws + OFF_COUNTS, 0, (size_t)(OFF_CURSOR + N_NODES * 4 - OFF_COUNTS),
                 stream);

  // CSR build
  hipLaunchKernelGGL(hist_kernel, dim3((N_EDGES + 255) / 256), dim3(256), 0,
                     stream, erow, counts);
  hipLaunchKernelGGL(scan_phase1, dim3(SCAN_BLOCKS), dim3(256), 0, stream,
                     counts, bsums);
  hipLaunchKernelGGL(scan_phase2, dim3(1), dim3(128), 0, stream, bsums);
  hipLaunchKernelGGL(scan_phase3, dim3(SCAN_BLOCKS), dim3(256), 0, stream,
                     counts, bsums);
  hipLaunchKernelGGL(build_kernel, dim3((N_EDGES + 255) / 256), dim3(256), 0,
                     stream, erow, ecol, eval, counts, cursor, csr_col, csr_val);

  // out = tanh(A_csr * support)
  hipLaunchKernelGGL(agg_kernel, dim3(N_NODES), dim3(128), 0, stream, counts,
                     csr_col, csr_val, support, out);
}

// Round 3
// 424.993 us; speedup vs baseline: 2.2128x; 1.3859x over previous
//
#include <hip/hip_runtime.h>
#include <math.h>

#define N_NODES 100000
#define N_EDGES 1600000
#define D_IN 256
#define D_OUT 128

#define BN 64
#define BK 32

// ---- workspace layout (bytes) ------------------------------------------
// support : float[N_NODES*D_OUT]             @ 0           (51,200,000)
// counts  : int[N_NODES+1] (-> offsets)      @ 51,200,000  (   400,004)
// csr_ev  : int2[N_EDGES] {col, val-bits}    @ 51,600,008  (12,800,000)
// bsums   : int[SCAN_BLOCKS]                 @ 64,400,008  (       392)
// pos_e   : int[N_EDGES] lives in d_out (free until agg overwrites it)
#define OFF_SUPPORT 0
#define OFF_COUNTS  51200000
#define OFF_CSREV   51600008
#define OFF_BSUMS   64400008

#define SCAN_CHUNK  1024
#define SCAN_BLOCKS ((N_NODES + SCAN_CHUNK - 1) / SCAN_CHUNK)  // 98

#define GEMM_BLOCKS ((N_NODES + BN - 1) / BN)  // 1563
#define GEMM_SPLIT  860                        // GEMM blocks riding in K1
#define EDGE_BLOCKS ((N_EDGES + 255) / 256)    // 6250

// ---------------------------------------------------------------------------
// GEMM body: support[n][f] = sum_k input[n][k]*W[k][f] + b[f]
// 64 nodes x 128 feats per block, 8x4 register micro-tile per thread.
// ---------------------------------------------------------------------------
__device__ __forceinline__ void gemm_body(
    int gb, const float* __restrict__ input, const float* __restrict__ W,
    const float* __restrict__ b, float* __restrict__ support) {
  __shared__ float As[BK][BN + 4];
  __shared__ float Ws[BK][D_OUT];

  const int t = threadIdx.x;
  const int node0 = gb * BN;
  const int fg = t & 31;
  const int ng = t >> 5;

  float acc[8][4];
#pragma unroll
  for (int i = 0; i < 8; i++)
#pragma unroll
    for (int j = 0; j < 4; j++) acc[i][j] = 0.f;

  for (int k0 = 0; k0 < D_IN; k0 += BK) {
#pragma unroll
    for (int j = 0; j < 2; j++) {
      int i = t + j * 256;
      int an = i >> 3;
      int ak = (i & 7) << 2;
      float4 v = make_float4(0.f, 0.f, 0.f, 0.f);
      if (node0 + an < N_NODES)
        v = *(const float4*)(input + (size_t)(node0 + an) * D_IN + k0 + ak);
      As[ak + 0][an] = v.x;
      As[ak + 1][an] = v.y;
      As[ak + 2][an] = v.z;
      As[ak + 3][an] = v.w;
    }
#pragma unroll
    for (int j = 0; j < 4; j++) {
      int i = t + j * 256;
      int wk = i >> 5;
      int wf = (i & 31) << 2;
      *(float4*)&Ws[wk][wf] = *(const float4*)(W + (size_t)(k0 + wk) * D_OUT + wf);
    }
    __syncthreads();

#pragma unroll 8
    for (int k = 0; k < BK; k++) {
      float4 w4 = *(const float4*)&Ws[k][fg << 2];
      float4 a0 = *(const float4*)&As[k][ng << 3];
      float4 a1 = *(const float4*)&As[k][(ng << 3) + 4];
      float a[8] = {a0.x, a0.y, a0.z, a0.w, a1.x, a1.y, a1.z, a1.w};
      float w[4] = {w4.x, w4.y, w4.z, w4.w};
#pragma unroll
      for (int i = 0; i < 8; i++)
#pragma unroll
        for (int j = 0; j < 4; j++)
          acc[i][j] = fmaf(a[i], w[j], acc[i][j]);
    }
    __syncthreads();
  }

  const float4 bv = *(const float4*)(b + (fg << 2));
#pragma unroll
  for (int i = 0; i < 8; i++) {
    int n = node0 + (ng << 3) + i;
    if (n < N_NODES) {
      float4 o;
      o.x = acc[i][0] + bv.x;
      o.y = acc[i][1] + bv.y;
      o.z = acc[i][2] + bv.z;
      o.w = acc[i][3] + bv.w;
      *(float4*)(support + (size_t)n * D_OUT + (fg << 2)) = o;
    }
  }
}

// K1: GEMM part A  ||  hist (degree count + per-edge position)
__global__ __launch_bounds__(256) void gemm_hist_kernel(
    const float* __restrict__ input, const float* __restrict__ W,
    const float* __restrict__ b, float* __restrict__ support,
    const int* __restrict__ erow, int* __restrict__ counts,
    int* __restrict__ pos_e) {
  if (blockIdx.x < GEMM_SPLIT) {
    gemm_body(blockIdx.x, input, W, b, support);
  } else {
    int e = (blockIdx.x - GEMM_SPLIT) * 256 + threadIdx.x;
    if (e < N_EDGES) pos_e[e] = atomicAdd(&counts[erow[e]], 1);
  }
}

// K2: GEMM part B  ||  build (atomic-free bucket scatter of packed int2)
__global__ __launch_bounds__(256) void gemm_build_kernel(
    const float* __restrict__ input, const float* __restrict__ W,
    const float* __restrict__ b, float* __restrict__ support,
    const int* __restrict__ erow, const int* __restrict__ ecol,
    const float* __restrict__ eval, const int* __restrict__ offsets,
    const int* __restrict__ pos_e, int2* __restrict__ csr_ev) {
  if (blockIdx.x < GEMM_BLOCKS - GEMM_SPLIT) {
    gemm_body(blockIdx.x + GEMM_SPLIT, input, W, b, support);
  } else {
    int e = (blockIdx.x - (GEMM_BLOCKS - GEMM_SPLIT)) * 256 + threadIdx.x;
    if (e < N_EDGES) {
      int idx = offsets[erow[e]] + pos_e[e];
      csr_ev[idx] = make_int2(ecol[e], __float_as_int(eval[e]));
    }
  }
}

// ---------------------------------------------------------------------------
// 3-phase exclusive scan over counts (unchanged, verified round 2)
// ---------------------------------------------------------------------------
__global__ __launch_bounds__(256) void scan_phase1(const int* __restrict__ counts,
                                                   int* __restrict__ bsums) {
  __shared__ int ts[256];
  int t = threadIdx.x;
  int idx0 = blockIdx.x * SCAN_CHUNK + t * 4;
  int s = 0;
#pragma unroll
  for (int i = 0; i < 4; i++)
    if (idx0 + i < N_NODES) s += counts[idx0 + i];
  ts[t] = s;
  __syncthreads();
#pragma unroll
  for (int off = 128; off > 0; off >>= 1) {
    if (t < off) ts[t] += ts[t + off];
    __syncthreads();
  }
  if (t == 0) bsums[blockIdx.x] = ts[0];
}

__global__ __launch_bounds__(128) void scan_phase2(int* __restrict__ bsums) {
  __shared__ int s[128];
  int t = threadIdx.x;
  int v = (t < SCAN_BLOCKS) ? bsums[t] : 0;
  s[t] = v;
  __syncthreads();
#pragma unroll
  for (int off = 1; off < 128; off <<= 1) {
    int x = (t >= off) ? s[t - off] : 0;
    __syncthreads();
    s[t] += x;
    __syncthreads();
  }
  if (t < SCAN_BLOCKS) bsums[t] = s[t] - v;  // exclusive
}

__global__ __launch_bounds__(256) void scan_phase3(int* __restrict__ counts,
                                                   const int* __restrict__ bsums) {
  __shared__ int ts[256];
  int t = threadIdx.x;
  int b = blockIdx.x;
  int idx0 = b * SCAN_CHUNK + t * 4;
  int v[4];
  int s = 0;
#pragma unroll
  for (int i = 0; i < 4; i++) {
    v[i] = (idx0 + i < N_NODES) ? counts[idx0 + i] : 0;
    s += v[i];
  }
  ts[t] = s;
  __syncthreads();
#pragma unroll
  for (int off = 1; off < 256; off <<= 1) {
    int x = (t >= off) ? ts[t - off] : 0;
    __syncthreads();
    ts[t] += x;
    __syncthreads();
  }
  int run = bsums[b] + ts[t] - s;
#pragma unroll
  for (int i = 0; i < 4; i++) {
    int idx = idx0 + i;
    if (idx < N_NODES) counts[idx] = run;
    run += v[i];
  }
  if (b == 0 && t == 0) counts[N_NODES] = N_EDGES;
}

// ---------------------------------------------------------------------------
// Gather-aggregate + fused tanh, 4x unrolled for memory-level parallelism.
// ---------------------------------------------------------------------------
__global__ __launch_bounds__(128) void agg_kernel(
    const int* __restrict__ offsets, const int2* __restrict__ csr_ev,
    const float* __restrict__ support, float* __restrict__ out) {
  int r = blockIdx.x;
  int f = threadIdx.x;
  int beg = offsets[r];
  int end = offsets[r + 1];
  float acc = 0.f;
  int j = beg;
  for (; j + 4 <= end; j += 4) {
    int2 e0 = csr_ev[j + 0];
    int2 e1 = csr_ev[j + 1];
    int2 e2 = csr_ev[j + 2];
    int2 e3 = csr_ev[j + 3];
    float s0 = support[(size_t)e0.x * D_OUT + f];
    float s1 = support[(size_t)e1.x * D_OUT + f];
    float s2 = support[(size_t)e2.x * D_OUT + f];
    float s3 = support[(size_t)e3.x * D_OUT + f];
    acc = fmaf(__int_as_float(e0.y), s0, acc);
    acc = fmaf(__int_as_float(e1.y), s1, acc);
    acc = fmaf(__int_as_float(e2.y), s2, acc);
    acc = fmaf(__int_as_float(e3.y), s3, acc);
  }
  for (; j < end; j++) {
    int2 ev = csr_ev[j];
    acc = fmaf(__int_as_float(ev.y), support[(size_t)ev.x * D_OUT + f], acc);
  }
  out[(size_t)r * D_OUT + f] = tanhf(acc);
}

extern "C" void kernel_launch(void* const* d_in, const int* in_sizes, int n_in,
                              void* d_out, int out_size, void* d_ws, size_t ws_size,
                              hipStream_t stream) {
  const float* input = (const float*)d_in[0];
  const int* erow = (const int*)d_in[1];
  const int* ecol = (const int*)d_in[2];
  const float* eval = (const float*)d_in[3];
  const float* W = (const float*)d_in[4];
  const float* b = (const float*)d_in[5];
  float* out = (float*)d_out;

  char* ws = (char*)d_ws;
  float* support = (float*)(ws + OFF_SUPPORT);
  int* counts = (int*)(ws + OFF_COUNTS);  // becomes offsets after scan
  int2* csr_ev = (int2*)(ws + OFF_CSREV);
  int* bsums = (int*)(ws + OFF_BSUMS);
  int* pos_e = (int*)d_out;  // d_out as scratch; agg overwrites it last

  hipMemsetAsync(ws + OFF_COUNTS, 0, (size_t)(N_NODES + 1) * 4, stream);

  // K1: GEMM part A || histogram (+ per-edge position into d_out scratch)
  hipLaunchKernelGGL(gemm_hist_kernel, dim3(GEMM_SPLIT + EDGE_BLOCKS), dim3(256),
                     0, stream, input, W, b, support, erow, counts, pos_e);
  // exclusive scan: counts -> offsets
  hipLaunchKernelGGL(scan_phase1, dim3(SCAN_BLOCKS), dim3(256), 0, stream,
                     counts, bsums);
  hipLaunchKernelGGL(scan_phase2, dim3(1), dim3(128), 0, stream, bsums);
  hipLaunchKernelGGL(scan_phase3, dim3(SCAN_BLOCKS), dim3(256), 0, stream,
                     counts, bsums);
  // K2: GEMM part B || atomic-free CSR bucket scatter
  hipLaunchKernelGGL(gemm_build_kernel,
                     dim3((GEMM_BLOCKS - GEMM_SPLIT) + EDGE_BLOCKS), dim3(256),
                     0, stream, input, W, b, support, erow, ecol, eval, counts,
                     pos_e, csr_ev);
  // out = tanh(A_csr * support)
  hipLaunchKernelGGL(agg_kernel, dim3(N_NODES), dim3(128), 0, stream, counts,
                     csr_ev, support, out);
}